// Round 17
// baseline (1374.032 us; speedup 1.0000x reference)
//
#include <hip/hip_runtime.h>
#include <stdint.h>

#define HH   128
#define NLAY 3
#define RR   32
#define OO   48
#define BBX  64
#define FFX  32
#define LLX  (RR + OO - 1)    /* 79 */
#define RBr  (RR * BBX)       /* 2048 */
#define N6   (6 * HH)         /* 768 */
#define TSTEPS (LLX + NLAY - 1)  /* 81 */
#define NBLOCKS 192

typedef unsigned short u16;
typedef __attribute__((ext_vector_type(8))) short short8;
typedef __attribute__((ext_vector_type(4))) float f32x4;

// ---- workspace layout ----
#define OFF_ABUF0 ((size_t)0)
#define SZ_ABUF0  ((size_t)LLX * RBr * FFX * 2)
#define OFF_HZ    (OFF_ABUF0 + SZ_ABUF0)
#define SZ_HZ     ((size_t)NLAY * 2 * RBr * 256 * 2)   /* [l][slot][2048][256] bf16 */
#define OFF_BAR   (OFF_HZ + SZ_HZ)
#define SZ_BAR    ((size_t)32768)
/* barG @+0, table @+256, arrival @+4096 (+bblk*2048, 24 slots x 64B),
   epoch @+24576 (+bblk*256) */
#define SZ_STATE  (SZ_HZ + SZ_BAR)

__device__ __forceinline__ u16 f2b(float x) {
  uint32_t u = __float_as_uint(x);
  return (u16)((u + 0x7FFFu + ((u >> 16) & 1u)) >> 16);
}
__device__ __forceinline__ float rcp_(float x) { return __builtin_amdgcn_rcpf(x); }
__device__ __forceinline__ float sigmoidf_(float x) {
  return rcp_(1.0f + __expf(-x));
}
__device__ __forceinline__ float tanhf_(float x) {
  return 1.0f - 2.0f * rcp_(__expf(2.0f * x) + 1.0f);
}

__global__ __launch_bounds__(256) void k_prep_input(const float* __restrict__ inp,
                                                    u16* __restrict__ abuf0) {
  int idx = blockIdx.x * 256 + threadIdx.x;
  if (idx >= LLX * RBr * FFX) return;
  int f   = idx & (FFX - 1);
  int row = (idx >> 5) & (RBr - 1);
  int s   = idx / (RBr * FFX);
  int g = row >> 6, b = row & 63;
  int o = s - g;
  float v = (o >= 0 && o < OO) ? inp[((b * RR + g) * OO + o) * FFX + f] : 0.0f;
  abuf0[idx] = f2b(v);
}

__global__ __launch_bounds__(256) void k_zero(uint32_t* __restrict__ p, size_t nwords) {
  size_t i = (size_t)blockIdx.x * 256 + threadIdx.x;
  size_t stride = (size_t)gridDim.x * 256;
  for (; i < nwords; i += stride) p[i] = 0u;
}

// ---- stage W into LDS in MFMA fragment-consumption order (conflict-free) ----
template <int KK>
__device__ __forceinline__ void stage_w(const float* __restrict__ Wsrc, int jblk,
                                        u16* __restrict__ Wl) {
  constexpr int NFRAG = (KK / 32) * 6;     // 54 or 96
  for (int e = threadIdx.x; e < NFRAG * 64; e += 1024) {
    int kcm = e >> 6, ln = e & 63;
    int kc = kcm / 6, m = kcm - kc * 6;
    int fr2 = ln & 15, hi2 = ln >> 4;
    int srow = m * 128 + jblk * 16 + fr2;
    const float* src = Wsrc + (size_t)srow * KK + kc * 32 + hi2 * 8;
    short8 v;
#pragma unroll
    for (int x = 0; x < 8; ++x) v[x] = (short)f2b(src[x]);
    *(short8*)&Wl[(size_t)e * 8] = v;
  }
}

// Gate-split pairing: wave w in 0..7 ("low") computes gates {0,1,4} -> hr for
// row-quad w; wave w+8 ("high") computes gates {2,3,5} -> hc for the same quad.
// Dual A-tiles: each W fragment read feeds 2 MFMAs. No cross-wave exchange.
// Register-budgeted for the 64-VGPR cap at 1024 threads: no explicit rings,
// no store-late buffers (compiler schedules loads within the budget).
template <int KK>
__device__ __forceinline__ void persist_body(char* __restrict__ ws,
                                             const float* __restrict__ Bias_l,
                                             float* __restrict__ out,
                                             int layer, int jblk, int bblk, bool light,
                                             u16* __restrict__ Wl,
                                             float* __restrict__ hcl,
                                             uint32_t* __restrict__ arrC,
                                             uint32_t* __restrict__ epoC,
                                             bool leader) {
  constexpr int NCH = KK / 32;
  const int tid = threadIdx.x;
  const int lane = tid & 63, w = tid >> 6;
  const int wq = w & 7;                          // row-quad: groups {4wq..4wq+3}
  const bool low = (w < 8);                      // low: hr gates; high: hc gates
  const int fr = lane & 15, hi = lane >> 4;
  const int myslot = layer * 8 + jblk;

  const int bcol = bblk * 8 + (fr & 7);
  const int g00   = wq * 4 + (fr >> 3);          // tile 0 fragment rows
  const int arow0 = g00 * 64 + bcol;
  const int arp0  = ((g00 + 1) & 31) * 64 + bcol;
  const int arow1 = (g00 + 2) * 64 + bcol;       // tile 1
  const int arp1  = ((g00 + 3) & 31) * 64 + bcol;
  const int j = jblk * 16 + fr;
  // W fragment bases for this half's 3 gates (m in {0,1,4} or {2,3,5})
  const u16* wfrag = &Wl[lane * 8];
  const u16* wA = wfrag + (size_t)(low ? 0 : 2) * 512;
  const u16* wB = wfrag + (size_t)(low ? 1 : 3) * 512;
  const u16* wC = wfrag + (size_t)(low ? 4 : 5) * 512;
  float bia[3];
  bia[0] = Bias_l[(low ? 0 : 2) * 128 + j];
  bia[1] = Bias_l[(low ? 1 : 3) * 128 + j];
  bia[2] = Bias_l[(low ? 4 : 5) * 128 + j];

  u16*   hz_base  = (u16*)(ws + OFF_HZ) + (size_t)layer * 2 * RBr * 256;
  u16*   hzp_base = (u16*)(ws + OFF_HZ) + (size_t)(layer - 1) * 2 * RBr * 256;
  u16*   abuf0    = (u16*)(ws + OFF_ABUF0);
  float* hid_row  = out + (size_t)RBr * LLX * 256;
  float* hid_col  = hid_row + (size_t)BBX * NLAY * RR * HH;

  float hr_reg[2][4];                            // hr state (low waves only)
#pragma unroll
  for (int t2 = 0; t2 < 2; ++t2)
#pragma unroll
    for (int q = 0; q < 4; ++q) hr_reg[t2][q] = 0.0f;

  for (int t = 0; t < TSTEPS; ++t) {
    const int s = t - layer;
    const uint32_t target = (uint32_t)(t + 1);

    if (s >= 0 && s < LLX) {
      const int sW = s & 1, sR = sW ^ 1;
      const u16* hzR = hz_base + (size_t)sR * RBr * 256;
      u16*       hzW = hz_base + (size_t)sW * RBr * 256;
      const u16* hzP = hzp_base + (size_t)sW * RBr * 256;  // prev layer, slice s
      const u16* ab_s = abuf0 + (size_t)s * RBr * FFX;
      const float* hcR = hcl + sR * 4352;
      float*       hcW = hcl + sW * 4352;

      if (wq * 4 <= s) {
        // ---- active quad: dual-tile GEMM over this half's 3 gates ----
        auto LDK = [&](int ar, int ap, int kc) -> short8 {
          if (kc < 8)
            return *(const short8*)&hzR[ar * 256 + kc * 32 + hi * 8];
          if constexpr (KK == 288) {
            return *(const short8*)&ab_s[ar * FFX + hi * 8];
          } else {
            if (kc < 12)
              return *(const short8*)&hzP[ar * 256 + (kc - 8) * 32 + hi * 8];
            return *(const short8*)&hzP[ap * 256 + 128 + (kc - 12) * 32 + hi * 8];
          }
        };

        f32x4 z4 = {0.f, 0.f, 0.f, 0.f};
        f32x4 acc0[3], acc1[3];
#pragma unroll
        for (int m = 0; m < 3; ++m) { acc0[m] = z4; acc1[m] = z4; }

        __builtin_amdgcn_s_setprio(1);
#pragma unroll
        for (int kc = 0; kc < NCH; ++kc) {
          short8 a0 = LDK(arow0, arp0, kc);
          short8 a1 = LDK(arow1, arp1, kc);
          short8 bvA = *(const short8*)&wA[(size_t)kc * 3072];
          short8 bvB = *(const short8*)&wB[(size_t)kc * 3072];
          short8 bvC = *(const short8*)&wC[(size_t)kc * 3072];
          acc0[0] = __builtin_amdgcn_mfma_f32_16x16x32_bf16(a0, bvA, acc0[0], 0, 0, 0);
          acc1[0] = __builtin_amdgcn_mfma_f32_16x16x32_bf16(a1, bvA, acc1[0], 0, 0, 0);
          acc0[1] = __builtin_amdgcn_mfma_f32_16x16x32_bf16(a0, bvB, acc0[1], 0, 0, 0);
          acc1[1] = __builtin_amdgcn_mfma_f32_16x16x32_bf16(a1, bvB, acc1[1], 0, 0, 0);
          acc0[2] = __builtin_amdgcn_mfma_f32_16x16x32_bf16(a0, bvC, acc0[2], 0, 0, 0);
          acc1[2] = __builtin_amdgcn_mfma_f32_16x16x32_bf16(a1, bvC, acc1[2], 0, 0, 0);
        }
        __builtin_amdgcn_s_setprio(0);

        // ---- half-epilogue, both tiles, stores inline ----
#pragma unroll
        for (int t2 = 0; t2 < 2; ++t2) {
          const f32x4* A = t2 ? acc1 : acc0;
          const int g = wq * 4 + 2 * t2 + (hi >> 1);
          const int gp = (g + 1) & (RR - 1);
          const float msk = (g <= s && s < RR) ? 1.0f : 0.0f;
#pragma unroll
          for (int q = 0; q < 4; ++q) {
            const int lb = (hi & 1) * 4 + q;
            const int b  = bblk * 8 + lb;
            const int row = g * 64 + b;
            if (low) {
              float ur  = sigmoidf_(A[0][q] + msk * bia[0]);
              float orw = sigmoidf_(A[1][q] + msk * bia[1]);
              float ir  = tanhf_(A[2][q] + msk * bia[2]);
              float hr_n = tanhf_((1.0f - ur) * hr_reg[t2][q] + ur * ir) * orw;
              hr_reg[t2][q] = hr_n;
              hzW[row * 256 + j] = f2b(hr_n);
              if (layer == 2)
                out[((size_t)row * LLX + s) * 256 + j] = hr_n;
              if (s - g == OO - 1)
                hid_row[((size_t)(b * NLAY + layer) * RR + g) * HH + j] = hr_n;
            } else {
              const int lrow = g * 8 + lb;
              const int rp = gp * 64 + b;
              const int lrp = gp * 8 + lb;
              float uc = sigmoidf_(A[0][q] + msk * bia[0]);
              float oc = sigmoidf_(A[1][q] + msk * bia[1]);
              float ic = tanhf_(A[2][q] + msk * bia[2]);
              float hc_n = tanhf_((1.0f - uc) * hcR[lrow * 17 + fr] + uc * ic) * oc;
              hcW[lrp * 17 + fr] = hc_n;
              hzW[rp * 256 + HH + j] = f2b(hc_n);
              if (layer == 2)
                out[((size_t)row * LLX + s) * 256 + HH + j] = hc_n;
              if (g == RR - 1 && s >= RR - 1)
                hid_col[((size_t)(b * NLAY + layer) * OO + (s - (RR - 1))) * HH + j] = hc_n;
            }
          }
        }
      } else {
        // ---- fully-inactive quad: all outputs exactly zero; store them ----
#pragma unroll
        for (int t2 = 0; t2 < 2; ++t2) {
          const int g = wq * 4 + 2 * t2 + (hi >> 1);
          const int gp = (g + 1) & (RR - 1);
#pragma unroll
          for (int q = 0; q < 4; ++q) {
            const int lb = (hi & 1) * 4 + q;
            const int b  = bblk * 8 + lb;
            const int row = g * 64 + b;
            if (low) {
              hzW[row * 256 + j] = 0;
              if (layer == 2)
                out[((size_t)row * LLX + s) * 256 + j] = 0.0f;
            } else {
              const int rp = gp * 64 + b;
              const int lrp = gp * 8 + lb;
              hcW[lrp * 17 + fr] = 0.0f;
              hzW[rp * 256 + HH + j] = 0;
              if (layer == 2)
                out[((size_t)row * LLX + s) * 256 + HH + j] = 0.0f;
            }
          }
        }
      }
    }

    // ---- arrive: all waves' state stores drained by syncthreads ----
    __syncthreads();
    if (tid == 0) {
      if (!light) __threadfence();
      __hip_atomic_store(&arrC[myslot * 16], target, __ATOMIC_RELAXED,
                         __HIP_MEMORY_SCOPE_AGENT);
    }
    // ---- wait: leader gathers 24 slots in parallel, publishes epoch ----
    if (leader) {
      if (tid < 24) {
        while (__hip_atomic_load(&arrC[tid * 16], __ATOMIC_RELAXED,
                                 __HIP_MEMORY_SCOPE_AGENT) < target)
          __builtin_amdgcn_s_sleep(1);
      }
      __syncthreads();
      if (tid == 0)
        __hip_atomic_store(epoC, target, __ATOMIC_RELAXED, __HIP_MEMORY_SCOPE_AGENT);
    }
    if (tid == 0) {
      while (__hip_atomic_load(epoC, __ATOMIC_RELAXED, __HIP_MEMORY_SCOPE_AGENT) < target)
        __builtin_amdgcn_s_sleep(1);
      if (!light) __threadfence();
    }
    __syncthreads();
    if (light) asm volatile("buffer_inv" ::: "memory");
  }
}

__global__ __launch_bounds__(1024, 4) void k_persist(char* __restrict__ ws,
                                                     const float* __restrict__ Wf,
                                                     const float* __restrict__ Wo,
                                                     const float* __restrict__ Bias,
                                                     float* __restrict__ out) {
  __shared__ u16 Wl[49152];       // 96 KiB: W slice, fragment-contiguous
  __shared__ float hcl[8704];     // 34 KiB: hc state, dbuf, stride-17
  __shared__ uint32_t sh_light;
  const int bx = blockIdx.x;
  const int layer = bx >> 6, jblk = (bx >> 3) & 7, bblk = bx & 7;
  const int tid = threadIdx.x;

  if (layer == 0) stage_w<288>(Wf, jblk, Wl);
  else            stage_w<512>(Wo + (size_t)(layer - 1) * N6 * 512, jblk, Wl);
  for (int e = tid; e < 8704; e += 1024) hcl[e] = 0.0f;

  // placement check: one-time global heavy barrier + per-component XCD match
  uint32_t xcc;
  asm volatile("s_getreg_b32 %0, hwreg(20, 0, 4)" : "=s"(xcc));
  uint32_t* barG  = (uint32_t*)(ws + OFF_BAR);
  uint32_t* table = (uint32_t*)(ws + OFF_BAR + 256);
  uint32_t* arrC  = (uint32_t*)(ws + OFF_BAR + 4096 + (size_t)bblk * 2048);
  uint32_t* epoC  = (uint32_t*)(ws + OFF_BAR + 24576 + (size_t)bblk * 256);
  const bool leader = (layer == 0 && jblk == 0);
  __syncthreads();
  if (tid == 0) {
    __hip_atomic_store(&table[bx], xcc, __ATOMIC_RELAXED, __HIP_MEMORY_SCOPE_AGENT);
    __hip_atomic_fetch_add(barG, 1u, __ATOMIC_RELEASE, __HIP_MEMORY_SCOPE_AGENT);
    while (__hip_atomic_load(barG, __ATOMIC_ACQUIRE, __HIP_MEMORY_SCOPE_AGENT) < NBLOCKS)
      __builtin_amdgcn_s_sleep(1);
    uint32_t lt = 1u;
    for (int q2 = 0; q2 < 24; ++q2) {
      uint32_t v = __hip_atomic_load(&table[q2 * 8 + bblk], __ATOMIC_RELAXED,
                                     __HIP_MEMORY_SCOPE_AGENT);
      lt &= (v == xcc) ? 1u : 0u;
    }
    sh_light = lt;
  }
  __syncthreads();
  const bool light = (sh_light != 0u);

  const float* bias_l = Bias + layer * N6;
  if (layer == 0)
    persist_body<288>(ws, bias_l, out, 0, jblk, bblk, light, Wl, hcl,
                      arrC, epoC, leader);
  else
    persist_body<512>(ws, bias_l, out, layer, jblk, bblk, light, Wl, hcl,
                      arrC, epoC, leader);
}

extern "C" void kernel_launch(void* const* d_in, const int* in_sizes, int n_in,
                              void* d_out, int out_size, void* d_ws, size_t ws_size,
                              hipStream_t stream) {
  const float* inp  = (const float*)d_in[0];
  const float* Wf   = (const float*)d_in[1];
  const float* Wo   = (const float*)d_in[2];
  const float* Bias = (const float*)d_in[3];
  float* out = (float*)d_out;
  char* ws = (char*)d_ws;
  (void)in_sizes; (void)n_in; (void)out_size; (void)ws_size;

  k_prep_input<<<(LLX * RBr * FFX) / 256, 256, 0, stream>>>(inp, (u16*)(ws + OFF_ABUF0));
  k_zero<<<2048, 256, 0, stream>>>((uint32_t*)(ws + OFF_HZ), SZ_STATE / 4);
  k_persist<<<NBLOCKS, 1024, 0, stream>>>(ws, Wf, Wo, Bias, out);
}

// Round 18
// 1367.600 us; speedup vs baseline: 1.0047x; 1.0047x over previous
//
#include <hip/hip_runtime.h>
#include <stdint.h>

#define HH   128
#define NLAY 3
#define RR   32
#define OO   48
#define BBX  64
#define FFX  32
#define LLX  (RR + OO - 1)    /* 79 */
#define RBr  (RR * BBX)       /* 2048 */
#define N6   (6 * HH)         /* 768 */
#define TSTEPS (LLX + NLAY - 1)  /* 81 */
#define NBLOCKS 192

typedef unsigned short u16;
typedef unsigned int u32;
typedef __attribute__((ext_vector_type(8))) short short8;
typedef __attribute__((ext_vector_type(4))) float f32x4;

// ---- workspace layout ----
#define OFF_ABUF0 ((size_t)0)
#define SZ_ABUF0  ((size_t)LLX * RBr * FFX * 2)
#define OFF_HZ    (OFF_ABUF0 + SZ_ABUF0)
#define SZ_HZ     ((size_t)NLAY * 2 * RBr * 256 * 2)   /* [l][slot][2048][256] bf16 */
#define OFF_BAR   (OFF_HZ + SZ_HZ)
#define SZ_BAR    ((size_t)32768)
/* barG @+0, table @+256, arrival @+4096 (+bblk*2048, 24 slots x 64B),
   epoch @+24576 (+bblk*256) */
#define SZ_STATE  (SZ_HZ + SZ_BAR)

__device__ __forceinline__ u16 f2b(float x) {
  uint32_t u = __float_as_uint(x);
  return (u16)((u + 0x7FFFu + ((u >> 16) & 1u)) >> 16);
}
__device__ __forceinline__ float rcp_(float x) { return __builtin_amdgcn_rcpf(x); }
__device__ __forceinline__ float sigmoidf_(float x) {
  return rcp_(1.0f + __expf(-x));
}
__device__ __forceinline__ float tanhf_(float x) {
  return 1.0f - 2.0f * rcp_(__expf(2.0f * x) + 1.0f);
}

__global__ __launch_bounds__(256) void k_prep_input(const float* __restrict__ inp,
                                                    u16* __restrict__ abuf0) {
  int idx = blockIdx.x * 256 + threadIdx.x;
  if (idx >= LLX * RBr * FFX) return;
  int f   = idx & (FFX - 1);
  int row = (idx >> 5) & (RBr - 1);
  int s   = idx / (RBr * FFX);
  int g = row >> 6, b = row & 63;
  int o = s - g;
  float v = (o >= 0 && o < OO) ? inp[((b * RR + g) * OO + o) * FFX + f] : 0.0f;
  abuf0[idx] = f2b(v);
}

__global__ __launch_bounds__(256) void k_zero(uint32_t* __restrict__ p, size_t nwords) {
  size_t i = (size_t)blockIdx.x * 256 + threadIdx.x;
  size_t stride = (size_t)gridDim.x * 256;
  for (; i < nwords; i += stride) p[i] = 0u;
}

// ---- stage W into LDS in MFMA fragment-consumption order (conflict-free) ----
template <int KK>
__device__ __forceinline__ void stage_w(const float* __restrict__ Wsrc, int jblk,
                                        u16* __restrict__ Wl) {
  constexpr int NFRAG = (KK / 32) * 6;     // 54 or 96
  for (int e = threadIdx.x; e < NFRAG * 64; e += 1024) {
    int kcm = e >> 6, ln = e & 63;
    int kc = kcm / 6, m = kcm - kc * 6;
    int fr2 = ln & 15, hi2 = ln >> 4;
    int srow = m * 128 + jblk * 16 + fr2;
    const float* src = Wsrc + (size_t)srow * KK + kc * 32 + hi2 * 8;
    short8 v;
#pragma unroll
    for (int x = 0; x < 8; ++x) v[x] = (short)f2b(src[x]);
    *(short8*)&Wl[(size_t)e * 8] = v;
  }
}

// Gate-split pairing (r17 semantics, addressing diet): wave w<8 ("low") does
// gates {0,1,4} -> hr; wave w+8 ("high") does gates {2,3,5} -> hc, for row-quad
// (w&7) as dual A-tiles. W-stream halved: 768 ds_read_b128/block/step.
// All hot-loop indexing u32; A-loads = uniform SGPR base + precomputed voffset.
template <int KK>
__device__ __forceinline__ void persist_body(char* __restrict__ ws,
                                             const float* __restrict__ Bias_l,
                                             float* __restrict__ out,
                                             int layer, int jblk, int bblk, bool light,
                                             u16* __restrict__ Wl,
                                             float* __restrict__ hcl,
                                             uint32_t* __restrict__ arrC,
                                             uint32_t* __restrict__ epoC,
                                             bool leader) {
  constexpr int NCH = KK / 32;
  const int tid = threadIdx.x;
  const int lane = tid & 63, w = tid >> 6;
  const int wq = w & 7;                          // row-quad: groups {4wq..4wq+3}
  const bool low = (w < 8);                      // low: hr gates; high: hc gates
  const int fr = lane & 15, hi = lane >> 4;
  const int myslot = layer * 8 + jblk;

  const int bcol = bblk * 8 + (fr & 7);
  const int g00   = wq * 4 + (fr >> 3);          // tile 0 fragment rows
  const int arow0 = g00 * 64 + bcol;
  const int arp0  = ((g00 + 1) & 31) * 64 + bcol;
  const int arow1 = (g00 + 2) * 64 + bcol;       // tile 1
  const int arp1  = ((g00 + 3) & 31) * 64 + bcol;
  const u32 j = (u32)(jblk * 16 + fr);
  // precomputed u32 A-load element offsets (u16 units)
  const u32 a0_hz = (u32)(arow0 * 256 + hi * 8);
  const u32 a1_hz = (u32)(arow1 * 256 + hi * 8);
  const u32 a0_rp = (u32)(arp0 * 256 + 128 + hi * 8);
  const u32 a1_rp = (u32)(arp1 * 256 + 128 + hi * 8);
  const u32 a0_ab = (u32)(arow0 * FFX + hi * 8);
  const u32 a1_ab = (u32)(arow1 * FFX + hi * 8);
  // W fragment bases for this half's 3 gates (m in {0,1,4} or {2,3,5})
  const u16* wA = Wl + (u32)lane * 8 + (u32)(low ? 0 : 2) * 512;
  const u16* wB = Wl + (u32)lane * 8 + (u32)(low ? 1 : 3) * 512;
  const u16* wC = Wl + (u32)lane * 8 + (u32)(low ? 4 : 5) * 512;
  float bia[3];
  bia[0] = Bias_l[(low ? 0 : 2) * 128 + j];
  bia[1] = Bias_l[(low ? 1 : 3) * 128 + j];
  bia[2] = Bias_l[(low ? 4 : 5) * 128 + j];

  u16*   hz_base  = (u16*)(ws + OFF_HZ) + (size_t)layer * 2 * RBr * 256;
  u16*   hzp_base = (u16*)(ws + OFF_HZ) + (size_t)(layer - 1) * 2 * RBr * 256;
  u16*   abuf0    = (u16*)(ws + OFF_ABUF0);
  float* hid_row  = out + (size_t)RBr * LLX * 256;
  float* hid_col  = hid_row + (size_t)BBX * NLAY * RR * HH;

  float hr_reg[2][4];                            // hr state (low waves only)
#pragma unroll
  for (int t2 = 0; t2 < 2; ++t2)
#pragma unroll
    for (int q = 0; q < 4; ++q) hr_reg[t2][q] = 0.0f;

  for (int t = 0; t < TSTEPS; ++t) {
    const int s = t - layer;
    const uint32_t target = (uint32_t)(t + 1);

    if (s >= 0 && s < LLX) {
      const u32 su = (u32)s;
      const int sW = s & 1, sR = sW ^ 1;
      const u16* hzR = hz_base + (u32)sR * (RBr * 256);
      u16*       hzW = hz_base + (u32)sW * (RBr * 256);
      const u16* hzP = hzp_base + (u32)sW * (RBr * 256);  // prev layer, slice s
      const u16* ab_s = abuf0 + (size_t)s * (RBr * FFX);
      const float* hcR = hcl + sR * 4352;
      float*       hcW = hcl + sW * 4352;

      if (wq * 4 <= s) {
        // ---- active quad: dual-tile GEMM over this half's 3 gates ----
        f32x4 z4 = {0.f, 0.f, 0.f, 0.f};
        f32x4 acc0[3], acc1[3];
#pragma unroll
        for (int m = 0; m < 3; ++m) { acc0[m] = z4; acc1[m] = z4; }

        __builtin_amdgcn_s_setprio(1);
#pragma unroll
        for (int kc = 0; kc < NCH; ++kc) {
          short8 a0, a1;
          if (kc < 8) {
            a0 = *(const short8*)&hzR[a0_hz + (u32)kc * 32];
            a1 = *(const short8*)&hzR[a1_hz + (u32)kc * 32];
          } else if constexpr (KK == 288) {
            a0 = *(const short8*)&ab_s[a0_ab];
            a1 = *(const short8*)&ab_s[a1_ab];
          } else if (kc < 12) {
            a0 = *(const short8*)&hzP[a0_hz + (u32)(kc - 8) * 32];
            a1 = *(const short8*)&hzP[a1_hz + (u32)(kc - 8) * 32];
          } else {
            a0 = *(const short8*)&hzP[a0_rp + (u32)(kc - 12) * 32];
            a1 = *(const short8*)&hzP[a1_rp + (u32)(kc - 12) * 32];
          }
          short8 bvA = *(const short8*)&wA[(u32)kc * 3072];
          short8 bvB = *(const short8*)&wB[(u32)kc * 3072];
          short8 bvC = *(const short8*)&wC[(u32)kc * 3072];
          acc0[0] = __builtin_amdgcn_mfma_f32_16x16x32_bf16(a0, bvA, acc0[0], 0, 0, 0);
          acc1[0] = __builtin_amdgcn_mfma_f32_16x16x32_bf16(a1, bvA, acc1[0], 0, 0, 0);
          acc0[1] = __builtin_amdgcn_mfma_f32_16x16x32_bf16(a0, bvB, acc0[1], 0, 0, 0);
          acc1[1] = __builtin_amdgcn_mfma_f32_16x16x32_bf16(a1, bvB, acc1[1], 0, 0, 0);
          acc0[2] = __builtin_amdgcn_mfma_f32_16x16x32_bf16(a0, bvC, acc0[2], 0, 0, 0);
          acc1[2] = __builtin_amdgcn_mfma_f32_16x16x32_bf16(a1, bvC, acc1[2], 0, 0, 0);
        }
        __builtin_amdgcn_s_setprio(0);

        // ---- half-epilogue, both tiles, stores inline, u32 indexing ----
#pragma unroll
        for (int t2 = 0; t2 < 2; ++t2) {
          const f32x4* A = t2 ? acc1 : acc0;
          const int g = wq * 4 + 2 * t2 + (hi >> 1);
          const int gp = (g + 1) & (RR - 1);
          const float msk = (g <= s && s < RR) ? 1.0f : 0.0f;
#pragma unroll
          for (int q = 0; q < 4; ++q) {
            const int lb = (hi & 1) * 4 + q;
            const int b  = bblk * 8 + lb;
            const u32 row = (u32)(g * 64 + b);
            if (low) {
              float ur  = sigmoidf_(A[0][q] + msk * bia[0]);
              float orw = sigmoidf_(A[1][q] + msk * bia[1]);
              float ir  = tanhf_(A[2][q] + msk * bia[2]);
              float hr_n = tanhf_((1.0f - ur) * hr_reg[t2][q] + ur * ir) * orw;
              hr_reg[t2][q] = hr_n;
              hzW[row * 256u + j] = f2b(hr_n);
              if (layer == 2)
                out[(row * (u32)LLX + su) * 256u + j] = hr_n;
              if (s - g == OO - 1)
                hid_row[((u32)(b * NLAY + layer) * (u32)RR + (u32)g) * 128u + j] = hr_n;
            } else {
              const int lrow = g * 8 + lb;
              const u32 rp = (u32)(gp * 64 + b);
              const int lrp = gp * 8 + lb;
              float uc = sigmoidf_(A[0][q] + msk * bia[0]);
              float oc = sigmoidf_(A[1][q] + msk * bia[1]);
              float ic = tanhf_(A[2][q] + msk * bia[2]);
              float hc_n = tanhf_((1.0f - uc) * hcR[lrow * 17 + fr] + uc * ic) * oc;
              hcW[lrp * 17 + fr] = hc_n;
              hzW[rp * 256u + 128u + j] = f2b(hc_n);
              if (layer == 2)
                out[(row * (u32)LLX + su) * 256u + 128u + j] = hc_n;
              if (g == RR - 1 && s >= RR - 1)
                hid_col[((u32)(b * NLAY + layer) * (u32)OO + (su - 31u)) * 128u + j] = hc_n;
            }
          }
        }
      } else {
        // ---- fully-inactive quad: all outputs exactly zero; store them ----
#pragma unroll
        for (int t2 = 0; t2 < 2; ++t2) {
          const int g = wq * 4 + 2 * t2 + (hi >> 1);
          const int gp = (g + 1) & (RR - 1);
#pragma unroll
          for (int q = 0; q < 4; ++q) {
            const int lb = (hi & 1) * 4 + q;
            const int b  = bblk * 8 + lb;
            const u32 row = (u32)(g * 64 + b);
            if (low) {
              hzW[row * 256u + j] = 0;
              if (layer == 2)
                out[(row * (u32)LLX + su) * 256u + j] = 0.0f;
            } else {
              const u32 rp = (u32)(gp * 64 + b);
              const int lrp = gp * 8 + lb;
              hcW[lrp * 17 + fr] = 0.0f;
              hzW[rp * 256u + 128u + j] = 0;
              if (layer == 2)
                out[(row * (u32)LLX + su) * 256u + 128u + j] = 0.0f;
            }
          }
        }
      }
    }

    // ---- arrive: all waves' state stores drained by syncthreads ----
    __syncthreads();
    if (tid == 0) {
      if (!light) __threadfence();
      __hip_atomic_store(&arrC[myslot * 16], target, __ATOMIC_RELAXED,
                         __HIP_MEMORY_SCOPE_AGENT);
    }
    // ---- wait: leader gathers 24 slots in parallel, publishes epoch ----
    if (leader) {
      if (tid < 24) {
        while (__hip_atomic_load(&arrC[tid * 16], __ATOMIC_RELAXED,
                                 __HIP_MEMORY_SCOPE_AGENT) < target)
          __builtin_amdgcn_s_sleep(1);
      }
      __syncthreads();
      if (tid == 0)
        __hip_atomic_store(epoC, target, __ATOMIC_RELAXED, __HIP_MEMORY_SCOPE_AGENT);
    }
    if (tid == 0) {
      while (__hip_atomic_load(epoC, __ATOMIC_RELAXED, __HIP_MEMORY_SCOPE_AGENT) < target)
        __builtin_amdgcn_s_sleep(1);
      if (!light) __threadfence();
    }
    __syncthreads();
    if (light) asm volatile("buffer_inv" ::: "memory");
  }
}

__global__ __launch_bounds__(1024, 4) void k_persist(char* __restrict__ ws,
                                                     const float* __restrict__ Wf,
                                                     const float* __restrict__ Wo,
                                                     const float* __restrict__ Bias,
                                                     float* __restrict__ out) {
  __shared__ u16 Wl[49152];       // 96 KiB: W slice, fragment-contiguous
  __shared__ float hcl[8704];     // 34 KiB: hc state, dbuf, stride-17
  __shared__ uint32_t sh_light;
  const int bx = blockIdx.x;
  const int layer = bx >> 6, jblk = (bx >> 3) & 7, bblk = bx & 7;
  const int tid = threadIdx.x;

  if (layer == 0) stage_w<288>(Wf, jblk, Wl);
  else            stage_w<512>(Wo + (size_t)(layer - 1) * N6 * 512, jblk, Wl);
  for (int e = tid; e < 8704; e += 1024) hcl[e] = 0.0f;

  // placement check: one-time global heavy barrier + per-component XCD match
  uint32_t xcc;
  asm volatile("s_getreg_b32 %0, hwreg(20, 0, 4)" : "=s"(xcc));
  uint32_t* barG  = (uint32_t*)(ws + OFF_BAR);
  uint32_t* table = (uint32_t*)(ws + OFF_BAR + 256);
  uint32_t* arrC  = (uint32_t*)(ws + OFF_BAR + 4096 + (size_t)bblk * 2048);
  uint32_t* epoC  = (uint32_t*)(ws + OFF_BAR + 24576 + (size_t)bblk * 256);
  const bool leader = (layer == 0 && jblk == 0);
  __syncthreads();
  if (tid == 0) {
    __hip_atomic_store(&table[bx], xcc, __ATOMIC_RELAXED, __HIP_MEMORY_SCOPE_AGENT);
    __hip_atomic_fetch_add(barG, 1u, __ATOMIC_RELEASE, __HIP_MEMORY_SCOPE_AGENT);
    while (__hip_atomic_load(barG, __ATOMIC_ACQUIRE, __HIP_MEMORY_SCOPE_AGENT) < NBLOCKS)
      __builtin_amdgcn_s_sleep(1);
    uint32_t lt = 1u;
    for (int q2 = 0; q2 < 24; ++q2) {
      uint32_t v = __hip_atomic_load(&table[q2 * 8 + bblk], __ATOMIC_RELAXED,
                                     __HIP_MEMORY_SCOPE_AGENT);
      lt &= (v == xcc) ? 1u : 0u;
    }
    sh_light = lt;
  }
  __syncthreads();
  const bool light = (sh_light != 0u);

  const float* bias_l = Bias + layer * N6;
  if (layer == 0)
    persist_body<288>(ws, bias_l, out, 0, jblk, bblk, light, Wl, hcl,
                      arrC, epoC, leader);
  else
    persist_body<512>(ws, bias_l, out, layer, jblk, bblk, light, Wl, hcl,
                      arrC, epoC, leader);
}

extern "C" void kernel_launch(void* const* d_in, const int* in_sizes, int n_in,
                              void* d_out, int out_size, void* d_ws, size_t ws_size,
                              hipStream_t stream) {
  const float* inp  = (const float*)d_in[0];
  const float* Wf   = (const float*)d_in[1];
  const float* Wo   = (const float*)d_in[2];
  const float* Bias = (const float*)d_in[3];
  float* out = (float*)d_out;
  char* ws = (char*)d_ws;
  (void)in_sizes; (void)n_in; (void)out_size; (void)ws_size;

  k_prep_input<<<(LLX * RBr * FFX) / 256, 256, 0, stream>>>(inp, (u16*)(ws + OFF_ABUF0));
  k_zero<<<2048, 256, 0, stream>>>((uint32_t*)(ws + OFF_HZ), SZ_STATE / 4);
  k_persist<<<NBLOCKS, 1024, 0, stream>>>(ws, Wf, Wo, Bias, out);
}

// Round 19
// 728.443 us; speedup vs baseline: 1.8863x; 1.8774x over previous
//
#include <hip/hip_runtime.h>
#include <stdint.h>

#define HH   128
#define NLAY 3
#define RR   32
#define OO   48
#define BBX  64
#define FFX  32
#define LLX  (RR + OO - 1)    /* 79 */
#define RBr  (RR * BBX)       /* 2048 */
#define N6   (6 * HH)         /* 768 */
#define TSTEPS (LLX + NLAY - 1)  /* 81 */
#define NBLOCKS 192

typedef unsigned short u16;
typedef __attribute__((ext_vector_type(8))) short short8;
typedef __attribute__((ext_vector_type(4))) float f32x4;

// ---- workspace layout ----
#define OFF_ABUF0 ((size_t)0)
#define SZ_ABUF0  ((size_t)LLX * RBr * FFX * 2)
#define OFF_HZ    (OFF_ABUF0 + SZ_ABUF0)
#define SZ_HZ     ((size_t)NLAY * 2 * RBr * 256 * 2)   /* [l][slot][2048][256] bf16 */
#define OFF_BAR   (OFF_HZ + SZ_HZ)
#define SZ_BAR    ((size_t)32768)
/* barG @+0, table @+256, arrival @+4096 (+bblk*2048, 24 slots x 64B) */
#define SZ_STATE  (SZ_HZ + SZ_BAR)

__device__ __forceinline__ u16 f2b(float x) {
  uint32_t u = __float_as_uint(x);
  return (u16)((u + 0x7FFFu + ((u >> 16) & 1u)) >> 16);
}
__device__ __forceinline__ float rcp_(float x) { return __builtin_amdgcn_rcpf(x); }
__device__ __forceinline__ float sigmoidf_(float x) {
  return rcp_(1.0f + __expf(-x));
}
__device__ __forceinline__ float tanhf_(float x) {
  return 1.0f - 2.0f * rcp_(__expf(2.0f * x) + 1.0f);
}

__global__ __launch_bounds__(256) void k_prep_input(const float* __restrict__ inp,
                                                    u16* __restrict__ abuf0) {
  int idx = blockIdx.x * 256 + threadIdx.x;
  if (idx >= LLX * RBr * FFX) return;
  int f   = idx & (FFX - 1);
  int row = (idx >> 5) & (RBr - 1);
  int s   = idx / (RBr * FFX);
  int g = row >> 6, b = row & 63;
  int o = s - g;
  float v = (o >= 0 && o < OO) ? inp[((b * RR + g) * OO + o) * FFX + f] : 0.0f;
  abuf0[idx] = f2b(v);
}

__global__ __launch_bounds__(256) void k_zero(uint32_t* __restrict__ p, size_t nwords) {
  size_t i = (size_t)blockIdx.x * 256 + threadIdx.x;
  size_t stride = (size_t)gridDim.x * 256;
  for (; i < nwords; i += stride) p[i] = 0u;
}

// ---- stage W into LDS in MFMA fragment-consumption order (conflict-free) ----
template <int KK>
__device__ __forceinline__ void stage_w(const float* __restrict__ Wsrc, int jblk,
                                        u16* __restrict__ Wl) {
  constexpr int NFRAG = (KK / 32) * 6;     // 54 or 96
  for (int e = threadIdx.x; e < NFRAG * 64; e += 1024) {
    int kcm = e >> 6, ln = e & 63;
    int kc = kcm / 6, m = kcm - kc * 6;
    int fr2 = ln & 15, hi2 = ln >> 4;
    int srow = m * 128 + jblk * 16 + fr2;
    const float* src = Wsrc + (size_t)srow * KK + kc * 32 + hi2 * 8;
    short8 v;
#pragma unroll
    for (int x = 0; x < 8; ++x) v[x] = (short)f2b(src[x]);
    *(short8*)&Wl[(size_t)e * 8] = v;
  }
}

template <int KK>
__device__ __forceinline__ void persist_body(char* __restrict__ ws,
                                             const float* __restrict__ Bias_l,
                                             float* __restrict__ out,
                                             int layer, int jblk, int bblk, bool light,
                                             u16* __restrict__ Wl,
                                             float* __restrict__ hcl,
                                             uint32_t* __restrict__ arrC) {
  constexpr int NCH = KK / 32;
  constexpr int RD  = 6;                         // A-load ring depth
  const int tid = threadIdx.x;
  const int lane = tid & 63, w = tid >> 6;       // 16 waves: wave w owns groups {2w, 2w+1}
  const int fr = lane & 15, hi = lane >> 4;
  const int myslot = layer * 8 + jblk;

  const int g0   = w * 2 + (fr >> 3);
  const int bcol = bblk * 8 + (fr & 7);
  const int arow = g0 * 64 + bcol;
  const int arp  = ((g0 + 1) & 31) * 64 + bcol;  // rolled row (hc source, prev layer)
  const int j = jblk * 16 + fr;
  const u16* wfrag = &Wl[lane * 8];
  float bia[6];
#pragma unroll
  for (int m = 0; m < 6; ++m) bia[m] = Bias_l[m * 128 + j];

  u16*   hz_base  = (u16*)(ws + OFF_HZ) + (size_t)layer * 2 * RBr * 256;
  u16*   hzp_base = (u16*)(ws + OFF_HZ) + (size_t)(layer - 1) * 2 * RBr * 256;
  u16*   abuf0    = (u16*)(ws + OFF_ABUF0);
  float* hid_row  = out + (size_t)RBr * LLX * 256;
  float* hid_col  = hid_row + (size_t)BBX * NLAY * RR * HH;

  float hr_reg[4];
#pragma unroll
  for (int q = 0; q < 4; ++q) hr_reg[q] = 0.0f;

  for (int t = 0; t < TSTEPS; ++t) {
    const int s = t - layer;
    const uint32_t target = (uint32_t)(t + 1);
    float sv_r[4], sv_c[4];                      // out/hid values, stored post-arrival
#pragma unroll
    for (int q = 0; q < 4; ++q) { sv_r[q] = 0.0f; sv_c[q] = 0.0f; }

    if (s >= 0 && s < LLX) {
      const int sW = s & 1, sR = sW ^ 1;
      const u16* hzR = hz_base + (size_t)sR * RBr * 256;
      u16*       hzW = hz_base + (size_t)sW * RBr * 256;
      const u16* hzP = hzp_base + (size_t)sW * RBr * 256;  // prev layer, slice s
      const u16* ab_s = abuf0 + (size_t)s * RBr * FFX;
      const float* hcR = hcl + sR * 4352;
      float*       hcW = hcl + sW * 4352;

      if (w * 2 <= s) {
        // ---------------- active wave: GEMM + state epilogue ----------------
        auto LDK = [&](int kc) -> short8 {
          if (kc < 8)
            return *(const short8*)&hzR[arow * 256 + kc * 32 + hi * 8];
          if constexpr (KK == 288) {
            return *(const short8*)&ab_s[arow * FFX + hi * 8];
          } else {
            if (kc < 12)
              return *(const short8*)&hzP[arow * 256 + (kc - 8) * 32 + hi * 8];
            return *(const short8*)&hzP[arp * 256 + 128 + (kc - 12) * 32 + hi * 8];
          }
        };

        f32x4 z4 = {0.f, 0.f, 0.f, 0.f};
        f32x4 acc[6];
#pragma unroll
        for (int m = 0; m < 6; ++m) acc[m] = z4;

        short8 ring[RD];
#pragma unroll
        for (int i = 0; i < RD && i < NCH; ++i) ring[i] = LDK(i);
        __builtin_amdgcn_s_setprio(1);
#pragma unroll
        for (int kc = 0; kc < NCH; ++kc) {
          short8 a = ring[kc % RD];
          if (kc + RD < NCH) ring[kc % RD] = LDK(kc + RD);
#pragma unroll
          for (int m = 0; m < 6; ++m) {
            short8 bv = *(const short8*)&wfrag[(size_t)(kc * 6 + m) * 512];
            acc[m] = __builtin_amdgcn_mfma_f32_16x16x32_bf16(a, bv, acc[m], 0, 0, 0);
          }
        }
        __builtin_amdgcn_s_setprio(0);

        const int g = w * 2 + (hi >> 1);
        const int gp = (g + 1) & (RR - 1);
        const float msk = (g <= s && s < RR) ? 1.0f : 0.0f;
        float mb[6];
#pragma unroll
        for (int m = 0; m < 6; ++m) mb[m] = msk * bia[m];
#pragma unroll
        for (int q = 0; q < 4; ++q) {
          const int lb = (hi & 1) * 4 + q;
          const int b  = bblk * 8 + lb;
          const int row = g * 64 + b;
          const int lrow = g * 8 + lb;
          const int rp = gp * 64 + b;
          const int lrp = gp * 8 + lb;
          float ur  = sigmoidf_(acc[0][q] + mb[0]);
          float orw = sigmoidf_(acc[1][q] + mb[1]);
          float uc  = sigmoidf_(acc[2][q] + mb[2]);
          float oc  = sigmoidf_(acc[3][q] + mb[3]);
          float ir  = tanhf_(acc[4][q] + mb[4]);
          float ic  = tanhf_(acc[5][q] + mb[5]);
          float hr_o = hr_reg[q];
          float hc_o = hcR[lrow * 17 + fr];
          float hr_n = tanhf_((1.0f - ur) * hr_o + ur * ir) * orw;
          float hc_n = tanhf_((1.0f - uc) * hc_o + uc * ic) * oc;
          hr_reg[q] = hr_n;
          sv_r[q] = hr_n;
          sv_c[q] = hc_n;
          hcW[lrp * 17 + fr] = hc_n;
          hzW[row * 256 + j] = f2b(hr_n);
          hzW[rp * 256 + HH + j] = f2b(hc_n);
        }
      } else {
        // -------- inactive wave: state zeros now; out zeros post-arrival --------
        const int g = w * 2 + (hi >> 1);
        const int gp = (g + 1) & (RR - 1);
#pragma unroll
        for (int q = 0; q < 4; ++q) {
          const int lb = (hi & 1) * 4 + q;
          const int b  = bblk * 8 + lb;
          const int row = g * 64 + b;
          const int rp = gp * 64 + b;
          const int lrp = gp * 8 + lb;
          hcW[lrp * 17 + fr] = 0.0f;
          hzW[row * 256 + j] = 0;
          hzW[rp * 256 + HH + j] = 0;
        }
      }
    }

    // ---- arrive: all waves' hz/hcl state stores drained by syncthreads ----
    __syncthreads();
    if (tid == 0) {
      if (!light) __threadfence();
      __hip_atomic_store(&arrC[myslot * 16], target, __ATOMIC_RELAXED,
                         __HIP_MEMORY_SCOPE_AGENT);
    }

    // ---- post-arrival: out/hid stores (no consumer this step) ----
    if (s >= 0 && s < LLX) {
      const int g = w * 2 + (hi >> 1);
#pragma unroll
      for (int q = 0; q < 4; ++q) {
        const int lb = (hi & 1) * 4 + q;
        const int b  = bblk * 8 + lb;
        const int row = g * 64 + b;
        if (layer == 2) {
          out[((size_t)row * LLX + s) * 256 + j] = sv_r[q];
          out[((size_t)row * LLX + s) * 256 + HH + j] = sv_c[q];
        }
        if (s - g == OO - 1)
          hid_row[((size_t)(b * NLAY + layer) * RR + g) * HH + j] = sv_r[q];
        if (g == RR - 1 && s >= RR - 1)
          hid_col[((size_t)(b * NLAY + layer) * OO + (s - (RR - 1))) * HH + j] = sv_c[q];
      }
    }

    // ---- wait: wave 0 polls ALL 24 slots directly (no leader/epoch hop) ----
    if (tid < 64) {
      const int slot = (tid < 24) ? tid : 0;
      while (__hip_atomic_load(&arrC[slot * 16], __ATOMIC_RELAXED,
                               __HIP_MEMORY_SCOPE_AGENT) < target)
        __builtin_amdgcn_s_sleep(1);
    }
    __syncthreads();
    if (!light) {
      if (tid == 0) __threadfence();
      __syncthreads();
    } else {
      asm volatile("buffer_inv" ::: "memory");
    }
  }
}

__global__ __launch_bounds__(1024, 4) void k_persist(char* __restrict__ ws,
                                                     const float* __restrict__ Wf,
                                                     const float* __restrict__ Wo,
                                                     const float* __restrict__ Bias,
                                                     float* __restrict__ out) {
  __shared__ u16 Wl[49152];       // 96 KiB: W slice, fragment-contiguous
  __shared__ float hcl[8704];     // 34 KiB: hc state, dbuf, stride-17
  __shared__ uint32_t sh_light;
  const int bx = blockIdx.x;
  const int layer = bx >> 6, jblk = (bx >> 3) & 7, bblk = bx & 7;
  const int tid = threadIdx.x;

  if (layer == 0) stage_w<288>(Wf, jblk, Wl);
  else            stage_w<512>(Wo + (size_t)(layer - 1) * N6 * 512, jblk, Wl);
  for (int e = tid; e < 8704; e += 1024) hcl[e] = 0.0f;

  // placement check: one-time global heavy barrier + per-component XCD match
  uint32_t xcc;
  asm volatile("s_getreg_b32 %0, hwreg(20, 0, 4)" : "=s"(xcc));
  uint32_t* barG  = (uint32_t*)(ws + OFF_BAR);
  uint32_t* table = (uint32_t*)(ws + OFF_BAR + 256);
  uint32_t* arrC  = (uint32_t*)(ws + OFF_BAR + 4096 + (size_t)bblk * 2048);
  __syncthreads();
  if (tid == 0) {
    __hip_atomic_store(&table[bx], xcc, __ATOMIC_RELAXED, __HIP_MEMORY_SCOPE_AGENT);
    __hip_atomic_fetch_add(barG, 1u, __ATOMIC_RELEASE, __HIP_MEMORY_SCOPE_AGENT);
    while (__hip_atomic_load(barG, __ATOMIC_ACQUIRE, __HIP_MEMORY_SCOPE_AGENT) < NBLOCKS)
      __builtin_amdgcn_s_sleep(1);
    uint32_t lt = 1u;
    for (int q2 = 0; q2 < 24; ++q2) {
      uint32_t v = __hip_atomic_load(&table[q2 * 8 + bblk], __ATOMIC_RELAXED,
                                     __HIP_MEMORY_SCOPE_AGENT);
      lt &= (v == xcc) ? 1u : 0u;
    }
    sh_light = lt;
  }
  __syncthreads();
  const bool light = (sh_light != 0u);

  const float* bias_l = Bias + layer * N6;
  if (layer == 0)
    persist_body<288>(ws, bias_l, out, 0, jblk, bblk, light, Wl, hcl, arrC);
  else
    persist_body<512>(ws, bias_l, out, layer, jblk, bblk, light, Wl, hcl, arrC);
}

extern "C" void kernel_launch(void* const* d_in, const int* in_sizes, int n_in,
                              void* d_out, int out_size, void* d_ws, size_t ws_size,
                              hipStream_t stream) {
  const float* inp  = (const float*)d_in[0];
  const float* Wf   = (const float*)d_in[1];
  const float* Wo   = (const float*)d_in[2];
  const float* Bias = (const float*)d_in[3];
  float* out = (float*)d_out;
  char* ws = (char*)d_ws;
  (void)in_sizes; (void)n_in; (void)out_size; (void)ws_size;

  k_prep_input<<<(LLX * RBr * FFX) / 256, 256, 0, stream>>>(inp, (u16*)(ws + OFF_ABUF0));
  k_zero<<<2048, 256, 0, stream>>>((uint32_t*)(ws + OFF_HZ), SZ_STATE / 4);
  k_persist<<<NBLOCKS, 1024, 0, stream>>>(ws, Wf, Wo, Bias, out);
}